// Round 1
// baseline (179.880 us; speedup 1.0000x reference)
//
#include <hip/hip_runtime.h>
#include <stdint.h>

#define BATCH 16
#define CIN   128
#define COUT  128
#define IMG_H 64
#define IMG_W 64
#define HW    4096          // 64*64
#define KTOT  1152          // 9*128, K order: k = khkw*128 + ci
#define BM    128
#define BN    128
#define BK    32
#define NSTEPS 36           // 1152/32
#define LDK   36            // padded LDS row stride (bf16 elems)

typedef __attribute__((ext_vector_type(8))) __bf16 bf16x8;
typedef __attribute__((ext_vector_type(4))) float  f32x4;

static __device__ __forceinline__ unsigned short f2bf(float f) {
  union { float f; uint32_t u; } c; c.f = f;
  uint32_t r = c.u + 0x7fffu + ((c.u >> 16) & 1u);   // RNE
  return (unsigned short)(r >> 16);
}

static __device__ __forceinline__ bf16x8 ld_frag8(const unsigned short* p) {
  uint2 lo = *(const uint2*)p;
  uint2 hi = *(const uint2*)(p + 4);
  uint4 w = make_uint4(lo.x, lo.y, hi.x, hi.y);
  return __builtin_bit_cast(bf16x8, w);
}

// ---- prep: weights fp32 [b][co][ci][kh][kw] -> bf16 [b][co][khkw*128+ci] ----
__global__ void prep_w(const float* __restrict__ w, unsigned short* __restrict__ wt) {
  __shared__ float buf[KTOT];
  const int bc = blockIdx.x;                      // b*COUT + co
  const float* src = w + (size_t)bc * KTOT;
  for (int i = threadIdx.x; i < KTOT; i += 128) buf[i] = src[i];
  __syncthreads();
  unsigned short* dst = wt + (size_t)bc * KTOT;
  for (int o = threadIdx.x; o < KTOT; o += 128) {
    const int khkw = o >> 7;
    const int ci   = o & 127;
    dst[o] = f2bf(buf[ci * 9 + khkw]);
  }
}

// ---- prep: features fp32 -> bf16, same [b][ci][h][w] layout ----
__global__ void prep_x(const float* __restrict__ x, unsigned short* __restrict__ xb) {
  const int i = blockIdx.x * 256 + threadIdx.x;
  const float4 v = ((const float4*)x)[i];
  ushort4 o;
  o.x = f2bf(v.x); o.y = f2bf(v.y); o.z = f2bf(v.z); o.w = f2bf(v.w);
  ((ushort4*)xb)[i] = o;
}

// ---- main implicit-GEMM: per sample C[128 x 4096] = W[128 x 1152] * im2col ----
__global__ __launch_bounds__(256, 2) void dynconv_gemm(
    const unsigned short* __restrict__ wt,   // [B][COUT][KTOT] bf16, khkw-major K
    const unsigned short* __restrict__ xb,   // [B][CIN][64][64] bf16
    float* __restrict__ out) {               // [B][COUT][64][64] fp32
  __shared__ alignas(16) unsigned short As[BM][LDK];
  __shared__ alignas(16) unsigned short Bs[BN][LDK];

  const int t    = threadIdx.x;
  const int b    = blockIdx.y;
  const int pix0 = blockIdx.x * BN;           // 128 pixels = 2 output rows
  const int oh0  = pix0 >> 6;

  const int lane = t & 63;
  const int wave = t >> 6;
  const int wm   = (wave & 1) << 6;           // M (co) offset of wave
  const int wn   = (wave >> 1) << 6;          // N (pixel) offset of wave
  const int l15  = lane & 15;
  const int quad = lane >> 4;

  // A staging: 512 chunks of 8 bf16; thread does chunk t and t+256
  const int a_co = t >> 2;
  const int a_c  = t & 3;
  // B staging: thread <-> (n, kq-half)
  const int n    = t & 127;
  const int q    = t >> 7;
  const int ow   = n & 63;
  const int ohl  = n >> 6;

  const unsigned short* wbase = wt + (size_t)b * COUT * KTOT;
  const unsigned short* xbase = xb + (size_t)b * CIN * HW;

  f32x4 acc[4][4] = {};

  for (int step = 0; step < NSTEPS; ++step) {
    const int k0   = step * BK;
    const int khkw = k0 >> 7;                 // uniform per step
    const int ci0  = k0 & 127;
    const int kh   = (khkw * 11) >> 5;        // khkw/3 for 0..8
    const int kw   = khkw - kh * 3;

    // ---- stage A tile (128 co x 32 k), contiguous 16B loads ----
    {
      const uint4 v0 = *(const uint4*)(wbase + a_co * KTOT + k0 + a_c * 8);
      const uint4 v1 = *(const uint4*)(wbase + (a_co + 64) * KTOT + k0 + a_c * 8);
      uint2* d0 = (uint2*)&As[a_co][a_c * 8];
      d0[0] = make_uint2(v0.x, v0.y);
      d0[1] = make_uint2(v0.z, v0.w);
      uint2* d1 = (uint2*)&As[a_co + 64][a_c * 8];
      d1[0] = make_uint2(v1.x, v1.y);
      d1[1] = make_uint2(v1.z, v1.w);
    }
    // ---- stage B tile (im2col: 32 k x 128 n), wave-uniform (kh,kw) ----
    {
      const int ih = oh0 + ohl + kh - 1;
      const int iw = ow + kw - 1;
      const bool inb = ((unsigned)ih < IMG_H) && ((unsigned)iw < IMG_W);
      const unsigned short* xp = xbase + (size_t)ci0 * HW + ih * IMG_W + iw;
#pragma unroll
      for (int i = 0; i < 4; ++i) {
        const int klq = q + 2 * i;            // 4-k chunk index, 0..7
        const unsigned short* p = xp + klq * 4 * HW;
        uint32_t e0 = inb ? (uint32_t)p[0]        : 0u;
        uint32_t e1 = inb ? (uint32_t)p[HW]       : 0u;
        uint32_t e2 = inb ? (uint32_t)p[2 * HW]   : 0u;
        uint32_t e3 = inb ? (uint32_t)p[3 * HW]   : 0u;
        *(uint2*)&Bs[n][klq * 4] = make_uint2(e0 | (e1 << 16), e2 | (e3 << 16));
      }
    }
    __syncthreads();

    bf16x8 af[4], bfr[4];
#pragma unroll
    for (int i = 0; i < 4; ++i) af[i]  = ld_frag8(&As[wm + i * 16 + l15][quad * 8]);
#pragma unroll
    for (int j = 0; j < 4; ++j) bfr[j] = ld_frag8(&Bs[wn + j * 16 + l15][quad * 8]);
#pragma unroll
    for (int i = 0; i < 4; ++i)
#pragma unroll
      for (int j = 0; j < 4; ++j)
        acc[i][j] = __builtin_amdgcn_mfma_f32_16x16x32_bf16(af[i], bfr[j], acc[i][j], 0, 0, 0);
    __syncthreads();
  }

  // ---- epilogue: D row = co = quad*4+r, col = pixel = l15 ----
  float* obase = out + (size_t)b * COUT * HW + pix0;
#pragma unroll
  for (int i = 0; i < 4; ++i) {
#pragma unroll
    for (int r = 0; r < 4; ++r) {
      const int row = wm + i * 16 + quad * 4 + r;
      float* orow = obase + (size_t)row * HW;
#pragma unroll
      for (int j = 0; j < 4; ++j)
        orow[wn + j * 16 + l15] = acc[i][j][r];
    }
  }
}

// ---- safety net if workspace is too small: direct fp32 conv ----
__global__ void dynconv_naive(const float* __restrict__ x, const float* __restrict__ w,
                              float* __restrict__ out) {
  const int o   = blockIdx.x * 256 + threadIdx.x;   // [b][co][pix]
  const int pix = o & (HW - 1);
  const int co  = (o >> 12) & (COUT - 1);
  const int b   = o >> 19;
  const int oh  = pix >> 6, ow = pix & 63;
  const float* xb = x + (size_t)b * CIN * HW;
  const float* wb = w + ((size_t)b * COUT + co) * CIN * 9;
  float s = 0.f;
  for (int ci = 0; ci < CIN; ++ci) {
    const float* xc = xb + ci * HW;
    const float* wc = wb + ci * 9;
#pragma unroll
    for (int kh = 0; kh < 3; ++kh) {
      const int ih = oh + kh - 1;
      if ((unsigned)ih >= IMG_H) continue;
#pragma unroll
      for (int kw = 0; kw < 3; ++kw) {
        const int iw = ow + kw - 1;
        if ((unsigned)iw >= IMG_W) continue;
        s += xc[ih * IMG_W + iw] * wc[kh * 3 + kw];
      }
    }
  }
  out[o] = s;
}

extern "C" void kernel_launch(void* const* d_in, const int* in_sizes, int n_in,
                              void* d_out, int out_size, void* d_ws, size_t ws_size,
                              hipStream_t stream) {
  const float* x = (const float*)d_in[0];   // features (16,128,64,64)
  const float* w = (const float*)d_in[1];   // dynamic_kernel (16,128,128,3,3)
  float* out = (float*)d_out;

  const size_t wt_bytes = (size_t)BATCH * COUT * KTOT * sizeof(unsigned short); //  4.7 MB
  const size_t xb_bytes = (size_t)BATCH * CIN * HW * sizeof(unsigned short);    // 16.8 MB

  if (ws_size >= wt_bytes + xb_bytes) {
    unsigned short* wt = (unsigned short*)d_ws;
    unsigned short* xbuf = (unsigned short*)((char*)d_ws + wt_bytes);
    prep_w<<<BATCH * COUT, 128, 0, stream>>>(w, wt);
    prep_x<<<(BATCH * CIN * HW) / (4 * 256), 256, 0, stream>>>(x, xbuf);
    dim3 grid(HW / BN, BATCH);
    dynconv_gemm<<<grid, 256, 0, stream>>>(wt, xbuf, out);
  } else {
    dynconv_naive<<<(BATCH * COUT * HW) / 256, 256, 0, stream>>>(x, w, out);
  }
}

// Round 2
// 161.850 us; speedup vs baseline: 1.1114x; 1.1114x over previous
//
#include <hip/hip_runtime.h>
#include <stdint.h>

#define BATCH 16
#define CIN   128
#define COUT  128
#define IMG_H 64
#define IMG_W 64
#define HW    4096          // 64*64
#define KTOT  1152          // 9*128, K order: k = khkw*128 + ci
#define XH    66            // padded rows
#define XW    66            // padded cols
#define BM    128
#define BN    128

typedef __attribute__((ext_vector_type(8))) __bf16 bf16x8;
typedef __attribute__((ext_vector_type(4))) float  f32x4;

static __device__ __forceinline__ unsigned short f2bf(float f) {
  union { float f; uint32_t u; } c; c.f = f;
  uint32_t r = c.u + 0x7fffu + ((c.u >> 16) & 1u);   // RNE
  return (unsigned short)(r >> 16);
}

static __device__ __forceinline__ bf16x8 ldg8(const unsigned short* p) {
  uint4 w = *(const uint4*)p;
  return __builtin_bit_cast(bf16x8, w);
}

// ---- prep: weights fp32 [b][co][ci][kh][kw] -> bf16 [b][co][khkw*128+ci] ----
__global__ void prep_w(const float* __restrict__ w, unsigned short* __restrict__ wt) {
  __shared__ float buf[KTOT];
  const int bc = blockIdx.x;                      // b*COUT + co
  const float* src = w + (size_t)bc * KTOT;
  for (int i = threadIdx.x; i < KTOT; i += 128) buf[i] = src[i];
  __syncthreads();
  unsigned short* dst = wt + (size_t)bc * KTOT;
  for (int o = threadIdx.x; o < KTOT; o += 128) {
    const int khkw = o >> 7;
    const int ci   = o & 127;
    dst[o] = f2bf(buf[ci * 9 + khkw]);
  }
}

// ---- prep: features fp32 NCHW -> bf16 NHWC with zero halo: xpad[b][66][66][128]
// one block per (b, h): transposes one image row (128 ci x 64 w) via LDS.
__global__ void prep_x(const float* __restrict__ x, unsigned short* __restrict__ xpad) {
  __shared__ uint32_t tile[64 * 68];              // [w][ci2], pad 68 words
  const int t = threadIdx.x;
  const int b = blockIdx.x >> 6;
  const int h = blockIdx.x & 63;
  const float* xb = x + (size_t)b * CIN * HW + h * IMG_W;
  uint32_t* xpw = (uint32_t*)xpad;                // bf16 pairs

  // phase 1: coalesced float4 reads, packed-u32 LDS writes
  const int lane16 = t & 15;
  const int g      = t >> 4;
#pragma unroll
  for (int it = 0; it < 4; ++it) {
    const int ci = it * 32 + g * 2;
    const float4 va = *(const float4*)(xb + (size_t)ci * HW + lane16 * 4);
    const float4 vb = *(const float4*)(xb + (size_t)(ci + 1) * HW + lane16 * 4);
    const float av[4] = {va.x, va.y, va.z, va.w};
    const float bv[4] = {vb.x, vb.y, vb.z, vb.w};
#pragma unroll
    for (int cc = 0; cc < 4; ++cc) {
      tile[(lane16 * 4 + cc) * 68 + it * 16 + g] =
          (uint32_t)f2bf(av[cc]) | ((uint32_t)f2bf(bv[cc]) << 16);
    }
  }
  __syncthreads();

  // phase 2: b128 LDS reads, coalesced global uint4 stores (interior row)
  const uint32_t base_w = (((uint32_t)b * XH + h + 1) * XW + 1) * 64;
#pragma unroll
  for (int it = 0; it < 4; ++it) {
    const int o = it * 256 + t;                   // uint4 index 0..1023
    const uint4 v = *(const uint4*)&tile[(o >> 4) * 68 + (o & 15) * 4];
    *(uint4*)&xpw[base_w + o * 4] = v;
  }

  // halo: col 0 and col 65 of this row
  if (t < 128) {
    const uint32_t row_w = ((uint32_t)b * XH + h + 1) * XW * 64;
    const int col = (t >> 6) ? 65 : 0;
    xpw[row_w + col * 64 + (t & 63)] = 0u;
  }
  // halo: full rows 0 and 65 (block h==0 does both)
  if (h == 0) {
    const uint32_t r0 = (uint32_t)b * XH * XW * 64;
    const uint32_t r65 = ((uint32_t)b * XH + 65) * XW * 64;
    for (int i = t; i < XW * 64; i += 256) {
      xpw[r0 + i] = 0u;
      xpw[r65 + i] = 0u;
    }
  }
}

// ---- main implicit-GEMM, no LDS, no barriers, register double-buffered ----
__global__ __launch_bounds__(256, 2) void dynconv_gemm(
    const unsigned short* __restrict__ wt,    // [B][COUT][KTOT] bf16
    const unsigned short* __restrict__ xpad,  // [B][66][66][128] bf16, halo=0
    float* __restrict__ out) {                // [B][COUT][64][64] fp32
  const int t    = threadIdx.x;
  const int b    = blockIdx.y;
  const int pix0 = blockIdx.x * BN;           // 128 pixels = 2 output rows
  const int oh0  = pix0 >> 6;

  const int lane = t & 63;
  const int wave = t >> 6;
  const int wm   = (wave & 1) << 6;           // M (co) offset
  const int wn   = (wave >> 1) << 6;          // N (pixel) offset
  const int l15  = lane & 15;
  const int quad = lane >> 4;
  const int ohl  = wn >> 6;

  const unsigned short* wb = wt + (size_t)b * COUT * KTOT;
  const unsigned short* xb = xpad + (size_t)b * XH * XW * CIN;

  const unsigned short* aptr[4];
  const unsigned short* bptr[4];
#pragma unroll
  for (int i = 0; i < 4; ++i)
    aptr[i] = wb + (size_t)(wm + i * 16 + l15) * KTOT + quad * 8;
#pragma unroll
  for (int j = 0; j < 4; ++j)
    bptr[j] = xb + (size_t)((oh0 + ohl) * XW + j * 16 + l15) * CIN + quad * 8;

  f32x4 acc[4][4] = {};

#define LOADSTEP(S, AF, BF)                                                  \
  {                                                                          \
    const int khkw_ = (S) >> 2, ci0_ = ((S) & 3) * 32;                       \
    const int kh_ = (khkw_ * 11) >> 5, kw_ = khkw_ - kh_ * 3;                \
    const int aoff_ = (S) * 32;                                              \
    const int boff_ = (kh_ * XW + kw_) * CIN + ci0_;                         \
    _Pragma("unroll") for (int i_ = 0; i_ < 4; ++i_)                         \
        AF[i_] = ldg8(aptr[i_] + aoff_);                                     \
    _Pragma("unroll") for (int j_ = 0; j_ < 4; ++j_)                         \
        BF[j_] = ldg8(bptr[j_] + boff_);                                     \
  }

#define MFMASTEP(AF, BF)                                                     \
  _Pragma("unroll") for (int i_ = 0; i_ < 4; ++i_)                           \
      _Pragma("unroll") for (int j_ = 0; j_ < 4; ++j_)                       \
          acc[i_][j_] = __builtin_amdgcn_mfma_f32_16x16x32_bf16(             \
              AF[i_], BF[j_], acc[i_][j_], 0, 0, 0);

  bf16x8 aA[4], bA[4], aB[4], bB[4];
  LOADSTEP(0, aA, bA);
#pragma unroll
  for (int s = 0; s < 36; s += 2) {
    LOADSTEP(s + 1, aB, bB);
    MFMASTEP(aA, bA);
    if (s + 2 < 36) LOADSTEP(s + 2, aA, bA);
    MFMASTEP(aB, bB);
  }
#undef LOADSTEP
#undef MFMASTEP

  // epilogue: D row = co = quad*4+r, col = pixel = l15
  float* obase = out + (size_t)b * COUT * HW + pix0;
#pragma unroll
  for (int i = 0; i < 4; ++i) {
#pragma unroll
    for (int r = 0; r < 4; ++r) {
      const int row = wm + i * 16 + quad * 4 + r;
      float* orow = obase + (size_t)row * HW;
#pragma unroll
      for (int j = 0; j < 4; ++j)
        orow[wn + j * 16 + l15] = acc[i][j][r];
    }
  }
}

// ---- safety net if workspace is too small: direct fp32 conv ----
__global__ void dynconv_naive(const float* __restrict__ x, const float* __restrict__ w,
                              float* __restrict__ out) {
  const int o   = blockIdx.x * 256 + threadIdx.x;   // [b][co][pix]
  const int pix = o & (HW - 1);
  const int co  = (o >> 12) & (COUT - 1);
  const int b   = o >> 19;
  const int oh  = pix >> 6, ow = pix & 63;
  const float* xb = x + (size_t)b * CIN * HW;
  const float* wb = w + ((size_t)b * COUT + co) * CIN * 9;
  float s = 0.f;
  for (int ci = 0; ci < CIN; ++ci) {
    const float* xc = xb + ci * HW;
    const float* wc = wb + ci * 9;
#pragma unroll
    for (int kh = 0; kh < 3; ++kh) {
      const int ih = oh + kh - 1;
      if ((unsigned)ih >= IMG_H) continue;
#pragma unroll
      for (int kw = 0; kw < 3; ++kw) {
        const int iw = ow + kw - 1;
        if ((unsigned)iw >= IMG_W) continue;
        s += xc[ih * IMG_W + iw] * wc[kh * 3 + kw];
      }
    }
  }
  out[o] = s;
}

extern "C" void kernel_launch(void* const* d_in, const int* in_sizes, int n_in,
                              void* d_out, int out_size, void* d_ws, size_t ws_size,
                              hipStream_t stream) {
  const float* x = (const float*)d_in[0];   // features (16,128,64,64)
  const float* w = (const float*)d_in[1];   // dynamic_kernel (16,128,128,3,3)
  float* out = (float*)d_out;

  const size_t wt_bytes = (size_t)BATCH * COUT * KTOT * sizeof(unsigned short);      //  4.72 MB
  const size_t xp_bytes = (size_t)BATCH * XH * XW * CIN * sizeof(unsigned short);    // 17.84 MB

  if (ws_size >= wt_bytes + xp_bytes) {
    unsigned short* wt = (unsigned short*)d_ws;
    unsigned short* xpad = (unsigned short*)((char*)d_ws + wt_bytes);
    prep_w<<<BATCH * COUT, 128, 0, stream>>>(w, wt);
    prep_x<<<BATCH * IMG_H, 256, 0, stream>>>(x, xpad);
    dim3 grid(HW / BN, BATCH);
    dynconv_gemm<<<grid, 256, 0, stream>>>(wt, xpad, out);
  } else {
    dynconv_naive<<<(BATCH * COUT * HW) / 256, 256, 0, stream>>>(x, w, out);
  }
}

// Round 4
// 132.661 us; speedup vs baseline: 1.3559x; 1.2200x over previous
//
#include <hip/hip_runtime.h>
#include <stdint.h>

#define BATCH 16
#define CIN   128
#define COUT  128
#define IMG_H 64
#define IMG_W 64
#define HW    4096
#define KTOT  1152          // 9*128
#define XH    66
#define XW    66
#define BM    128
#define BN    128
#define BK    64
#define NSTEPS 18           // 1152/64
#define ASTEP 8192          // elems per A step-tile: 8cq*128co*8e

typedef __attribute__((ext_vector_type(8))) __bf16 bf16x8;
typedef __attribute__((ext_vector_type(4))) float  f32x4;
typedef __attribute__((address_space(1))) const void* gas_p;
typedef __attribute__((address_space(3))) void*       las_p;

static __device__ __forceinline__ unsigned short f2bf(float f) {
  union { float f; uint32_t u; } c; c.f = f;
  uint32_t r = c.u + 0x7fffu + ((c.u >> 16) & 1u);   // RNE
  return (unsigned short)(r >> 16);
}

static __device__ __forceinline__ void gload_lds16(const unsigned short* g, unsigned short* l) {
  __builtin_amdgcn_global_load_lds((gas_p)g, (las_p)l, 16, 0, 0);
}

// ---- prep: w fp32 [b][co][ci][3][3] -> bf16 wt4[b][step18][cq8][co128][e8]
// step = khkw*2 + (ci>>6); within step: k'' = cq*8+e = ci&63.
__global__ void prep_w(const float* __restrict__ w, unsigned short* __restrict__ wt4) {
  const int b    = blockIdx.x / NSTEPS;
  const int step = blockIdx.x % NSTEPS;
  const int khkw = step >> 1;
  const int cib  = (step & 1) << 6;
  const float* wb = w + (size_t)b * COUT * KTOT;
  unsigned short* dst = wt4 + ((size_t)b * NSTEPS + step) * ASTEP;
#pragma unroll
  for (int i = 0; i < 4; ++i) {
    const int c  = i * 256 + threadIdx.x;       // chunk 0..1023
    const int cq = c >> 7;
    const int co = c & 127;
    const int ci0 = cib + cq * 8;
    const float* src = wb + (size_t)co * KTOT + (size_t)ci0 * 9 + khkw;
    uint32_t p[4];
#pragma unroll
    for (int e = 0; e < 4; ++e)
      p[e] = (uint32_t)f2bf(src[(2 * e) * 9]) | ((uint32_t)f2bf(src[(2 * e + 1) * 9]) << 16);
    *(uint4*)&dst[(size_t)c * 8] = make_uint4(p[0], p[1], p[2], p[3]);
  }
}

// ---- prep: x fp32 NCHW -> bf16 NHWC + zero halo: xpad[b][66][66][128] ----
__global__ void prep_x(const float* __restrict__ x, unsigned short* __restrict__ xpad) {
  __shared__ uint32_t tile[64 * 68];
  const int t = threadIdx.x;
  const int b = blockIdx.x >> 6;
  const int h = blockIdx.x & 63;
  const float* xb = x + (size_t)b * CIN * HW + h * IMG_W;
  uint32_t* xpw = (uint32_t*)xpad;

  const int lane16 = t & 15;
  const int g      = t >> 4;
#pragma unroll
  for (int it = 0; it < 4; ++it) {
    const int ci = it * 32 + g * 2;
    const float4 va = *(const float4*)(xb + (size_t)ci * HW + lane16 * 4);
    const float4 vb = *(const float4*)(xb + (size_t)(ci + 1) * HW + lane16 * 4);
    const float av[4] = {va.x, va.y, va.z, va.w};
    const float bv[4] = {vb.x, vb.y, vb.z, vb.w};
#pragma unroll
    for (int cc = 0; cc < 4; ++cc)
      tile[(lane16 * 4 + cc) * 68 + it * 16 + g] =
          (uint32_t)f2bf(av[cc]) | ((uint32_t)f2bf(bv[cc]) << 16);
  }
  __syncthreads();

  const uint32_t base_w = (((uint32_t)b * XH + h + 1) * XW + 1) * 64;
#pragma unroll
  for (int it = 0; it < 4; ++it) {
    const int o = it * 256 + t;
    const uint4 v = *(const uint4*)&tile[(o >> 4) * 68 + (o & 15) * 4];
    *(uint4*)&xpw[base_w + o * 4] = v;
  }
  if (t < 128) {
    const uint32_t row_w = ((uint32_t)b * XH + h + 1) * XW * 64;
    const int col = (t >> 6) ? 65 : 0;
    xpw[row_w + col * 64 + (t & 63)] = 0u;
  }
  if (h == 0) {
    const uint32_t r0  = (uint32_t)b * XH * XW * 64;
    const uint32_t r65 = ((uint32_t)b * XH + 65) * XW * 64;
    for (int i = t; i < XW * 64; i += 256) { xpw[r0 + i] = 0u; xpw[r65 + i] = 0u; }
  }
}

// ---- main implicit-GEMM: m97 structure, BK=64, conflict-free [cq][row][8] LDS ----
__global__ __launch_bounds__(256, 2) void dynconv_gemm(
    const unsigned short* __restrict__ wt4,   // [B][18][8][128][8] bf16
    const unsigned short* __restrict__ xpad,  // [B][66][66][128] bf16, halo=0
    float* __restrict__ out) {                // [B][COUT][64][64] fp32
  __shared__ alignas(16) unsigned short As[ASTEP];   // [cq8][co128][8]  16 KB
  __shared__ alignas(16) unsigned short Bs[ASTEP];   // [cq8][pix128][8] 16 KB

  const int t    = threadIdx.x;
  const int b    = blockIdx.y;
  const int pix0 = blockIdx.x * BN;
  const int oh0  = pix0 >> 6;

  const int lane = t & 63;
  const int wave = t >> 6;
  const int wm   = (wave & 1) << 6;
  const int wn   = (wave >> 1) << 6;
  const int l15  = lane & 15;
  const int quad = lane >> 4;

  // A source: thread's chunk c = i*256 + t lives at element c*8 = i*2048 + t*8
  const unsigned short* abase = wt4 + (size_t)b * NSTEPS * ASTEP + (size_t)t * 8;
  const unsigned short* xb    = xpad + (size_t)b * XH * XW * CIN;

  // B: thread's 4 chunks c = i*256 + t; pix = c&127, cq = c>>7 (thread-const parts)
  const unsigned short* bbase[4];
#pragma unroll
  for (int i = 0; i < 4; ++i) {
    const int c   = i * 256 + t;
    const int cq  = c >> 7;
    const int pix = c & 127;
    bbase[i] = xb + (size_t)((oh0 + (pix >> 6)) * XW + (pix & 63)) * CIN + cq * 8;
  }

  // LDS staging bases: wave-uniform (wave,i) only; lane writes at base + lane*16B
  unsigned short* alds[4];
  unsigned short* blds[4];
#pragma unroll
  for (int i = 0; i < 4; ++i) {
    alds[i] = &As[(i * 256 + wave * 64) * 8];
    blds[i] = &Bs[(i * 256 + wave * 64) * 8];
  }

  f32x4 acc[4][4] = {};

  for (int step = 0; step < NSTEPS; ++step) {
    const int khkw = step >> 1;
    const int kh   = (khkw * 11) >> 5;
    const int kw   = khkw - kh * 3;
    const int boff = (kh * XW + kw) * CIN + ((step & 1) << 6);
    const unsigned short* astep = abase + (size_t)step * ASTEP;

#pragma unroll
    for (int i = 0; i < 4; ++i) gload_lds16(astep + i * 256 * 8, alds[i]);
#pragma unroll
    for (int i = 0; i < 4; ++i) gload_lds16(bbase[i] + boff, blds[i]);
    __syncthreads();

#pragma unroll
    for (int ks = 0; ks < 2; ++ks) {
      const int cqb = (ks * 4 + quad) * 128;
      bf16x8 af[4], bf[4];
#pragma unroll
      for (int i = 0; i < 4; ++i) af[i] = *(const bf16x8*)&As[(cqb + wm + i * 16 + l15) * 8];
#pragma unroll
      for (int j = 0; j < 4; ++j) bf[j] = *(const bf16x8*)&Bs[(cqb + wn + j * 16 + l15) * 8];
#pragma unroll
      for (int i = 0; i < 4; ++i)
#pragma unroll
        for (int j = 0; j < 4; ++j)
          acc[i][j] = __builtin_amdgcn_mfma_f32_16x16x32_bf16(af[i], bf[j], acc[i][j], 0, 0, 0);
    }
    __syncthreads();
  }

  // epilogue: row = co = quad*4+r, col = pixel = l15
  float* obase = out + (size_t)b * COUT * HW + pix0;
#pragma unroll
  for (int i = 0; i < 4; ++i) {
#pragma unroll
    for (int r = 0; r < 4; ++r) {
      const int row = wm + i * 16 + quad * 4 + r;
      float* orow = obase + (size_t)row * HW;
#pragma unroll
      for (int j = 0; j < 4; ++j)
        orow[wn + j * 16 + l15] = acc[i][j][r];
    }
  }
}

// ---- safety net: direct fp32 conv ----
__global__ void dynconv_naive(const float* __restrict__ x, const float* __restrict__ w,
                              float* __restrict__ out) {
  const int o   = blockIdx.x * 256 + threadIdx.x;
  const int pix = o & (HW - 1);
  const int co  = (o >> 12) & (COUT - 1);
  const int b   = o >> 19;
  const int oh  = pix >> 6, ow = pix & 63;
  const float* xb = x + (size_t)b * CIN * HW;
  const float* wb = w + ((size_t)b * COUT + co) * CIN * 9;
  float s = 0.f;
  for (int ci = 0; ci < CIN; ++ci) {
    const float* xc = xb + ci * HW;
    const float* wc = wb + ci * 9;
#pragma unroll
    for (int kh = 0; kh < 3; ++kh) {
      const int ih = oh + kh - 1;
      if ((unsigned)ih >= IMG_H) continue;
#pragma unroll
      for (int kw = 0; kw < 3; ++kw) {
        const int iw = ow + kw - 1;
        if ((unsigned)iw >= IMG_W) continue;
        s += xc[ih * IMG_W + iw] * wc[kh * 3 + kw];
      }
    }
  }
  out[o] = s;
}

extern "C" void kernel_launch(void* const* d_in, const int* in_sizes, int n_in,
                              void* d_out, int out_size, void* d_ws, size_t ws_size,
                              hipStream_t stream) {
  const float* x = (const float*)d_in[0];
  const float* w = (const float*)d_in[1];
  float* out = (float*)d_out;

  const size_t wt_bytes = (size_t)BATCH * NSTEPS * ASTEP * sizeof(unsigned short);  //  4.72 MB
  const size_t xp_bytes = (size_t)BATCH * XH * XW * CIN * sizeof(unsigned short);   // 17.84 MB

  if (ws_size >= wt_bytes + xp_bytes) {
    unsigned short* wt4  = (unsigned short*)d_ws;
    unsigned short* xpad = (unsigned short*)((char*)d_ws + wt_bytes);
    prep_w<<<BATCH * NSTEPS, 256, 0, stream>>>(w, wt4);
    prep_x<<<BATCH * IMG_H, 256, 0, stream>>>(x, xpad);
    dim3 grid(HW / BN, BATCH);
    dynconv_gemm<<<grid, 256, 0, stream>>>(wt4, xpad, out);
  } else {
    dynconv_naive<<<(BATCH * COUT * HW) / 256, 256, 0, stream>>>(x, w, out);
  }
}

// Round 5
// 122.404 us; speedup vs baseline: 1.4696x; 1.0838x over previous
//
#include <hip/hip_runtime.h>
#include <stdint.h>

#define BATCH 16
#define CIN   128
#define COUT  128
#define IMG_H 64
#define IMG_W 64
#define HW    4096
#define KTOT  1152          // 9*128
#define XH    66
#define XW    66
#define NCQ   16            // ci groups of 8
#define BM    128
#define BN    64
#define BK    64
#define NSTEPS 18           // 1152/64
#define ASTEP 8192          // A elems per step-tile: 8cq*128co*8e
#define BSTEP 4096          // B elems per step-tile: 8cq*64pix*8e

typedef __attribute__((ext_vector_type(8))) __bf16 bf16x8;
typedef __attribute__((ext_vector_type(4))) float  f32x4;
typedef __attribute__((address_space(1))) const void* gas_p;
typedef __attribute__((address_space(3))) void*       las_p;

static __device__ __forceinline__ unsigned short f2bf(float f) {
  union { float f; uint32_t u; } c; c.f = f;
  uint32_t r = c.u + 0x7fffu + ((c.u >> 16) & 1u);   // RNE
  return (unsigned short)(r >> 16);
}

static __device__ __forceinline__ void gload_lds16(const unsigned short* g, unsigned short* l) {
  __builtin_amdgcn_global_load_lds((gas_p)g, (las_p)l, 16, 0, 0);
}

// ---- fused prep ----
// blocks [0, 1024): x fp32 NCHW -> bf16 xpad[b][66][16cq][66][8], zero halo
// blocks [1024, 1312): w fp32 [b][co][ci][3][3] -> wt4[b][step18][cq8][co128][e8]
__global__ void prep_fused(const float* __restrict__ x, const float* __restrict__ w,
                           unsigned short* __restrict__ wt4, unsigned short* __restrict__ xpad) {
  const int t = threadIdx.x;
  if (blockIdx.x < BATCH * IMG_H) {
    // ---------------- prep_x ----------------
    __shared__ uint32_t tile[64 * 68];              // [wcol][ci2], pad 68 words
    const int b = blockIdx.x >> 6;
    const int h = blockIdx.x & 63;
    const float* xb = x + (size_t)b * CIN * HW + h * IMG_W;
    uint4* xp4 = (uint4*)xpad;                      // 16B chunks

    const int lane16 = t & 15;
    const int g      = t >> 4;
#pragma unroll
    for (int it = 0; it < 4; ++it) {
      const int ci = it * 32 + g * 2;
      const float4 va = *(const float4*)(xb + (size_t)ci * HW + lane16 * 4);
      const float4 vb = *(const float4*)(xb + (size_t)(ci + 1) * HW + lane16 * 4);
      const float av[4] = {va.x, va.y, va.z, va.w};
      const float bv[4] = {vb.x, vb.y, vb.z, vb.w};
#pragma unroll
      for (int cc = 0; cc < 4; ++cc)
        tile[(lane16 * 4 + cc) * 68 + it * 16 + g] =
            (uint32_t)f2bf(av[cc]) | ((uint32_t)f2bf(bv[cc]) << 16);
    }
    __syncthreads();

    // interior: chunk o -> cqg = o>>6, wcol = o&63; dst chunk ((b*66+h+1)*16+cqg)*66 + wcol+1
    const uint32_t rbase = ((uint32_t)b * XH + h + 1) * NCQ;
#pragma unroll
    for (int it = 0; it < 4; ++it) {
      const int o   = it * 256 + t;
      const int cqg = o >> 6;
      const int wc  = o & 63;
      const uint4 v = *(const uint4*)&tile[wc * 68 + cqg * 4];
      xp4[(rbase + cqg) * XW + wc + 1] = v;
    }
    // col halo (w=0, w=65) for this row
    if (t < 32) {
      const int cqg = t & 15;
      const int col = (t >> 4) ? 65 : 0;
      xp4[(rbase + cqg) * XW + col] = make_uint4(0, 0, 0, 0);
    }
    // row halo (rows 0 and 65), done by h==0 blocks
    if (h == 0) {
      const uint32_t r0  = (uint32_t)b * XH * NCQ * XW;
      const uint32_t r65 = ((uint32_t)b * XH + 65) * NCQ * XW;
      for (int i = t; i < NCQ * XW; i += 256) {
        xp4[r0 + i]  = make_uint4(0, 0, 0, 0);
        xp4[r65 + i] = make_uint4(0, 0, 0, 0);
      }
    }
  } else {
    // ---------------- prep_w ----------------
    const int idx  = blockIdx.x - BATCH * IMG_H;
    const int b    = idx / NSTEPS;
    const int step = idx % NSTEPS;
    const int khkw = step >> 1;
    const int cib  = (step & 1) << 6;
    const float* wb = w + (size_t)b * COUT * KTOT;
    unsigned short* dst = wt4 + ((size_t)b * NSTEPS + step) * ASTEP;
#pragma unroll
    for (int i = 0; i < 4; ++i) {
      const int c  = i * 256 + t;                 // chunk 0..1023
      const int cq = c >> 7;
      const int co = c & 127;
      const int ci0 = cib + cq * 8;
      const float* src = wb + (size_t)co * KTOT + (size_t)ci0 * 9 + khkw;
      uint32_t p[4];
#pragma unroll
      for (int e = 0; e < 4; ++e)
        p[e] = (uint32_t)f2bf(src[(2 * e) * 9]) | ((uint32_t)f2bf(src[(2 * e + 1) * 9]) << 16);
      *(uint4*)&dst[(size_t)c * 8] = make_uint4(p[0], p[1], p[2], p[3]);
    }
  }
}

// ---- main implicit-GEMM: 128co x 64pix per block, 4 blocks/CU ----
__global__ __launch_bounds__(256, 4) void dynconv_gemm(
    const unsigned short* __restrict__ wt4,   // [B][18][8][128][8] bf16
    const unsigned short* __restrict__ xpad,  // [B][66][16][66][8] bf16, halo=0
    float* __restrict__ out) {                // [B][COUT][64][64] fp32
  __shared__ alignas(16) unsigned short As[ASTEP];   // [cq8][co128][8]  16 KB
  __shared__ alignas(16) unsigned short Bs[BSTEP];   // [cq8][pix64][8]   8 KB

  const int t    = threadIdx.x;
  const int b    = blockIdx.y;
  const int oh   = blockIdx.x;                // one output row per block

  const int lane = t & 63;
  const int wave = t >> 6;
  const int wm   = (wave & 1) << 6;           // co offset of wave (0/64)
  const int wn   = (wave >> 1) << 5;          // pixel offset of wave (0/32)
  const int l15  = lane & 15;
  const int quad = lane >> 4;

  // A source: thread's chunk c = i*256 + t at element c*8
  const unsigned short* abase = wt4 + (size_t)b * NSTEPS * ASTEP + (size_t)t * 8;
  // B source: thread-const part ((i*4+wave)*66 + lane)*8 ; step part added below
  const unsigned short* xb = xpad + (size_t)b * XH * NCQ * XW * 8;
  const unsigned short* bbase[2];
#pragma unroll
  for (int i = 0; i < 2; ++i)
    bbase[i] = xb + (size_t)(((i * 4 + wave) * XW) + lane) * 8;

  // LDS staging bases (wave-uniform; HW adds lane*16B)
  unsigned short* alds[4];
  unsigned short* blds[2];
#pragma unroll
  for (int i = 0; i < 4; ++i) alds[i] = &As[(i * 256 + wave * 64) * 8];
#pragma unroll
  for (int i = 0; i < 2; ++i) blds[i] = &Bs[((i * 4 + wave) * 64) * 8];

  f32x4 acc[4][2] = {};

  for (int step = 0; step < NSTEPS; ++step) {
    const int khkw = step >> 1;
    const int kh   = (khkw * 11) >> 5;
    const int kw   = khkw - kh * 3;
    // step part of B address: row = oh+kh, cq-group base = (step&1)*8, col shift kw
    const size_t boff = ((size_t)((oh + kh) * NCQ + ((step & 1) << 3)) * XW + kw) * 8;
    const unsigned short* astep = abase + (size_t)step * ASTEP;

#pragma unroll
    for (int i = 0; i < 4; ++i) gload_lds16(astep + i * 2048, alds[i]);
#pragma unroll
    for (int i = 0; i < 2; ++i) gload_lds16(bbase[i] + boff, blds[i]);
    __syncthreads();

#pragma unroll
    for (int ks = 0; ks < 2; ++ks) {
      const int cq = ks * 4 + quad;
      bf16x8 af[4], bf[2];
#pragma unroll
      for (int i = 0; i < 4; ++i) af[i] = *(const bf16x8*)&As[(cq * 128 + wm + i * 16 + l15) * 8];
#pragma unroll
      for (int j = 0; j < 2; ++j) bf[j] = *(const bf16x8*)&Bs[(cq * 64 + wn + j * 16 + l15) * 8];
#pragma unroll
      for (int i = 0; i < 4; ++i)
#pragma unroll
        for (int j = 0; j < 2; ++j)
          acc[i][j] = __builtin_amdgcn_mfma_f32_16x16x32_bf16(af[i], bf[j], acc[i][j], 0, 0, 0);
    }
    __syncthreads();
  }

  // epilogue: co = wm + i*16 + quad*4 + r; pix = oh*64 + wn + j*16 + l15
  float* obase = out + (size_t)b * COUT * HW + oh * 64;
#pragma unroll
  for (int i = 0; i < 4; ++i) {
#pragma unroll
    for (int r = 0; r < 4; ++r) {
      const int row = wm + i * 16 + quad * 4 + r;
      float* orow = obase + (size_t)row * HW;
#pragma unroll
      for (int j = 0; j < 2; ++j)
        orow[wn + j * 16 + l15] = acc[i][j][r];
    }
  }
}

// ---- safety net: direct fp32 conv ----
__global__ void dynconv_naive(const float* __restrict__ x, const float* __restrict__ w,
                              float* __restrict__ out) {
  const int o   = blockIdx.x * 256 + threadIdx.x;
  const int pix = o & (HW - 1);
  const int co  = (o >> 12) & (COUT - 1);
  const int b   = o >> 19;
  const int oh  = pix >> 6, ow = pix & 63;
  const float* xb = x + (size_t)b * CIN * HW;
  const float* wb = w + ((size_t)b * COUT + co) * CIN * 9;
  float s = 0.f;
  for (int ci = 0; ci < CIN; ++ci) {
    const float* xc = xb + ci * HW;
    const float* wc = wb + ci * 9;
#pragma unroll
    for (int kh = 0; kh < 3; ++kh) {
      const int ih = oh + kh - 1;
      if ((unsigned)ih >= IMG_H) continue;
#pragma unroll
      for (int kw = 0; kw < 3; ++kw) {
        const int iw = ow + kw - 1;
        if ((unsigned)iw >= IMG_W) continue;
        s += xc[ih * IMG_W + iw] * wc[kh * 3 + kw];
      }
    }
  }
  out[o] = s;
}

extern "C" void kernel_launch(void* const* d_in, const int* in_sizes, int n_in,
                              void* d_out, int out_size, void* d_ws, size_t ws_size,
                              hipStream_t stream) {
  const float* x = (const float*)d_in[0];
  const float* w = (const float*)d_in[1];
  float* out = (float*)d_out;

  const size_t wt_bytes = (size_t)BATCH * NSTEPS * ASTEP * sizeof(unsigned short);       //  4.72 MB
  const size_t xp_bytes = (size_t)BATCH * XH * NCQ * XW * 8 * sizeof(unsigned short);    // 17.84 MB

  if (ws_size >= wt_bytes + xp_bytes) {
    unsigned short* wt4  = (unsigned short*)d_ws;
    unsigned short* xpad = (unsigned short*)((char*)d_ws + wt_bytes);
    prep_fused<<<BATCH * IMG_H + BATCH * NSTEPS, 256, 0, stream>>>(x, w, wt4, xpad);
    dim3 grid(IMG_H, BATCH);
    dynconv_gemm<<<grid, 256, 0, stream>>>(wt4, xpad, out);
  } else {
    dynconv_naive<<<(BATCH * COUT * HW) / 256, 256, 0, stream>>>(x, w, out);
  }
}